// Round 1
// baseline (495.352 us; speedup 1.0000x reference)
//
#include <hip/hip_runtime.h>
#include <cstdint>
#include <cstddef>

typedef unsigned short u16;
typedef __attribute__((ext_vector_type(8))) short bf16x8;   // 8 bf16 = 4 VGPRs
typedef __attribute__((ext_vector_type(4))) float f32x4;

#define B_  4
#define Q_  1024
#define K_  2048
#define E_  1024
#define H_  16
#define HD_ 64

__device__ inline u16 f2bf(float f) {
  union { float f; uint32_t u; } x; x.f = f;
  uint32_t r = (x.u + 0x7fffu + ((x.u >> 16) & 1u)) >> 16;  // RNE
  return (u16)r;
}

// ---------------- f32 -> bf16 elementwise convert ----------------
__global__ __launch_bounds__(256) void cvt_f32_bf16(const float* __restrict__ in,
                                                    u16* __restrict__ out, int n) {
  int i = (blockIdx.x * 256 + threadIdx.x) * 8;
  if (i + 7 < n) {
    float4 a = *reinterpret_cast<const float4*>(in + i);
    float4 b = *reinterpret_cast<const float4*>(in + i + 4);
    union { u16 u[8]; uint4 v; } r;
    r.u[0] = f2bf(a.x); r.u[1] = f2bf(a.y); r.u[2] = f2bf(a.z); r.u[3] = f2bf(a.w);
    r.u[4] = f2bf(b.x); r.u[5] = f2bf(b.y); r.u[6] = f2bf(b.z); r.u[7] = f2bf(b.w);
    *reinterpret_cast<uint4*>(out + i) = r.v;
  }
}

// ---------------- W[K][N] f32 -> Wt[N][K] bf16 (LDS tiled) ----------------
__global__ __launch_bounds__(256) void transpose_cvt(const float* __restrict__ W,
                                                     u16* __restrict__ Wt, int Kc, int N) {
  __shared__ float t[64][65];
  int k0 = blockIdx.x * 64, n0 = blockIdx.y * 64;
  int r = threadIdx.x >> 6, c = threadIdx.x & 63;
#pragma unroll
  for (int i = 0; i < 16; ++i)
    t[r + i * 4][c] = W[(size_t)(k0 + r + i * 4) * N + n0 + c];
  __syncthreads();
#pragma unroll
  for (int i = 0; i < 16; ++i)
    Wt[(size_t)(n0 + r + i * 4) * Kc + k0 + c] = f2bf(t[c][r + i * 4]);
}

// ---------------- bf16 GEMM: C[M,N] = A[M,K] * Bt[N,K]^T ----------------
// MODE 0: C f32 row-major. MODE 1: C bf16 row-major.
// MODE 2: C bf16 written V-transposed: row=b*2048+kk, col=h*64+hd ->
//         C[((b*16+h)*64+hd)*2048 + kk]
template <int MODE>
__global__ __launch_bounds__(256) void gemm_bt(const u16* __restrict__ A,
                                               const u16* __restrict__ Bt,
                                               void* __restrict__ C,
                                               int M, int N, int Kc) {
  __shared__ u16 As[128 * 32];
  __shared__ u16 Bs[128 * 32];
  const int tid = threadIdx.x;
  const int w = tid >> 6, l = tid & 63;
  const int wr = w >> 1, wc = w & 1;
  const int lr = l & 15, lg = l >> 4;
  const int m0 = blockIdx.x * 128, n0 = blockIdx.y * 128;

  f32x4 acc[4][4];
#pragma unroll
  for (int mt = 0; mt < 4; ++mt)
#pragma unroll
    for (int nt = 0; nt < 4; ++nt)
      acc[mt][nt] = (f32x4){0.f, 0.f, 0.f, 0.f};

  for (int k0 = 0; k0 < Kc; k0 += 32) {
    uint4 av[2], bv[2];
#pragma unroll
    for (int c = 0; c < 2; ++c) {
      int off = (tid + c * 256) * 8;        // element offset in tile (8 bf16 = 16B)
      int row = off >> 5;                   // 32 bf16 per row
      int col = off & 31;
      av[c] = *reinterpret_cast<const uint4*>(A + (size_t)(m0 + row) * Kc + k0 + col);
      bv[c] = *reinterpret_cast<const uint4*>(Bt + (size_t)(n0 + row) * Kc + k0 + col);
    }
    __syncthreads();   // previous iteration's LDS reads done
#pragma unroll
    for (int c = 0; c < 2; ++c) {
      int off = (tid + c * 256) * 8;
      *reinterpret_cast<uint4*>(&As[off]) = av[c];
      *reinterpret_cast<uint4*>(&Bs[off]) = bv[c];
    }
    __syncthreads();

    bf16x8 a[4], b[4];
#pragma unroll
    for (int mt = 0; mt < 4; ++mt)
      a[mt] = *reinterpret_cast<const bf16x8*>(&As[(wr * 64 + mt * 16 + lr) * 32 + lg * 8]);
#pragma unroll
    for (int nt = 0; nt < 4; ++nt)
      b[nt] = *reinterpret_cast<const bf16x8*>(&Bs[(wc * 64 + nt * 16 + lr) * 32 + lg * 8]);
#pragma unroll
    for (int mt = 0; mt < 4; ++mt)
#pragma unroll
      for (int nt = 0; nt < 4; ++nt)
        acc[mt][nt] = __builtin_amdgcn_mfma_f32_16x16x32_bf16(a[mt], b[nt], acc[mt][nt], 0, 0, 0);
  }

#pragma unroll
  for (int mt = 0; mt < 4; ++mt) {
    int rbase = m0 + wr * 64 + mt * 16 + lg * 4;
#pragma unroll
    for (int nt = 0; nt < 4; ++nt) {
      int col = n0 + wc * 64 + nt * 16 + lr;
#pragma unroll
      for (int j = 0; j < 4; ++j) {
        int row = rbase + j;
        if (MODE == 0) {
          ((float*)C)[(size_t)row * N + col] = acc[mt][nt][j];
        } else if (MODE == 1) {
          ((u16*)C)[(size_t)row * N + col] = f2bf(acc[mt][nt][j]);
        } else {
          int bb = row >> 11, kk = row & 2047;
          int hh = col >> 6, hd = col & 63;
          ((u16*)C)[((size_t)((bb << 4) + hh) * 64 + hd) * 2048 + kk] = f2bf(acc[mt][nt][j]);
        }
      }
    }
  }
}

// ---------------- fused biased flash attention ----------------
// qp[b*Q+q][E] bf16, kp[b*K+kk][E] bf16, vT[(b*H+h)*HD+hd][K] bf16, bias[b][K] f32
// out attn[b*Q+q][E] bf16 (E index = h*64+hd)
__global__ __launch_bounds__(256) void attn_kernel(const u16* __restrict__ qp,
                                                   const u16* __restrict__ kp,
                                                   const u16* __restrict__ vT,
                                                   const float* __restrict__ bias,
                                                   u16* __restrict__ out) {
  __shared__ u16 q_lds[64 * 64];
  __shared__ u16 k_lds[64 * 64];
  __shared__ u16 v_lds[64 * 64];
  __shared__ u16 p_lds[4][16 * 64];

  const int blk = blockIdx.x;
  const int qt = blk & 15, h = (blk >> 4) & 15, b = blk >> 8;
  const int tid = threadIdx.x;
  const int w = tid >> 6, l = tid & 63;
  const int lr = l & 15, lg = l >> 4;

  // stage q tile [64 rows][64 hd]
#pragma unroll
  for (int c = 0; c < 2; ++c) {
    int o = tid * 8 + c * 2048;
    int row = o >> 6, col = o & 63;
    *reinterpret_cast<uint4*>(&q_lds[o]) =
        *reinterpret_cast<const uint4*>(qp + (size_t)(b * Q_ + qt * 64 + row) * E_ + h * 64 + col);
  }

  f32x4 O[4];
  float m_run[4], l_run[4];
#pragma unroll
  for (int j = 0; j < 4; ++j) {
    O[j] = (f32x4){0.f, 0.f, 0.f, 0.f};
    m_run[j] = -1e30f; l_run[j] = 0.f;
  }
  const float scale = 0.125f;  // 1/sqrt(64)
  const float* bias_b = bias + (size_t)b * K_;

  for (int kk0 = 0; kk0 < K_; kk0 += 64) {
    // prefetch k tile [64 kk][64 hd] and vT tile [64 hd][64 kk]
    uint4 kv[2], vv[2];
#pragma unroll
    for (int c = 0; c < 2; ++c) {
      int o = tid * 8 + c * 2048;
      int row = o >> 6, col = o & 63;
      kv[c] = *reinterpret_cast<const uint4*>(kp + (size_t)(b * K_ + kk0 + row) * E_ + h * 64 + col);
      vv[c] = *reinterpret_cast<const uint4*>(vT + (size_t)((b * H_ + h) * HD_ + row) * K_ + kk0 + col);
    }
    __syncthreads();   // prior iteration's MFMA reads done
#pragma unroll
    for (int c = 0; c < 2; ++c) {
      int o = tid * 8 + c * 2048;
      *reinterpret_cast<uint4*>(&k_lds[o]) = kv[c];
      *reinterpret_cast<uint4*>(&v_lds[o]) = vv[c];
    }
    __syncthreads();

    // QK^T: wave w covers q rows [w*16, w*16+16), all 64 kk
    bf16x8 qa[2];
#pragma unroll
    for (int ks = 0; ks < 2; ++ks)
      qa[ks] = *reinterpret_cast<const bf16x8*>(&q_lds[(w * 16 + lr) * 64 + ks * 32 + lg * 8]);

    f32x4 S[4];
#pragma unroll
    for (int ct = 0; ct < 4; ++ct) {
      f32x4 s = (f32x4){0.f, 0.f, 0.f, 0.f};
#pragma unroll
      for (int ks = 0; ks < 2; ++ks) {
        bf16x8 kb = *reinterpret_cast<const bf16x8*>(&k_lds[(ct * 16 + lr) * 64 + ks * 32 + lg * 8]);
        s = __builtin_amdgcn_mfma_f32_16x16x32_bf16(qa[ks], kb, s, 0, 0, 0);
      }
      S[ct] = s;
    }

    // scale + bias; per-row online softmax (row = lg*4+j, 16 lanes share a row)
    float tmax[4];
#pragma unroll
    for (int j = 0; j < 4; ++j) tmax[j] = -1e30f;
#pragma unroll
    for (int ct = 0; ct < 4; ++ct) {
      float bv = bias_b[kk0 + ct * 16 + lr];
#pragma unroll
      for (int j = 0; j < 4; ++j) {
        float sv = S[ct][j] * scale + bv;
        S[ct][j] = sv;
        tmax[j] = fmaxf(tmax[j], sv);
      }
    }
#pragma unroll
    for (int m = 1; m < 16; m <<= 1)
#pragma unroll
      for (int j = 0; j < 4; ++j)
        tmax[j] = fmaxf(tmax[j], __shfl_xor(tmax[j], m, 64));

    float mf[4], psum[4];
#pragma unroll
    for (int j = 0; j < 4; ++j) {
      float mnew = fmaxf(m_run[j], tmax[j]);
      mf[j] = __expf(m_run[j] - mnew);
      m_run[j] = mnew;
      psum[j] = 0.f;
    }
#pragma unroll
    for (int ct = 0; ct < 4; ++ct)
#pragma unroll
      for (int j = 0; j < 4; ++j) {
        float pv = __expf(S[ct][j] - m_run[j]);
        S[ct][j] = pv;
        psum[j] += pv;
      }
#pragma unroll
    for (int m = 1; m < 16; m <<= 1)
#pragma unroll
      for (int j = 0; j < 4; ++j)
        psum[j] += __shfl_xor(psum[j], m, 64);
#pragma unroll
    for (int j = 0; j < 4; ++j) {
      l_run[j] = l_run[j] * mf[j] + psum[j];
#pragma unroll
      for (int ht = 0; ht < 4; ++ht) O[ht][j] *= mf[j];
    }

    // P (bf16) -> per-wave LDS to re-fragment as PV A-operand
    u16* pw = &p_lds[w][0];
#pragma unroll
    for (int ct = 0; ct < 4; ++ct)
#pragma unroll
      for (int j = 0; j < 4; ++j)
        pw[(lg * 4 + j) * 64 + ct * 16 + lr] = f2bf(S[ct][j]);

    bf16x8 pa[2];
#pragma unroll
    for (int ks = 0; ks < 2; ++ks)
      pa[ks] = *reinterpret_cast<const bf16x8*>(&pw[lr * 64 + ks * 32 + lg * 8]);

#pragma unroll
    for (int ht = 0; ht < 4; ++ht)
#pragma unroll
      for (int ks = 0; ks < 2; ++ks) {
        bf16x8 vb = *reinterpret_cast<const bf16x8*>(&v_lds[(ht * 16 + lr) * 64 + ks * 32 + lg * 8]);
        O[ht] = __builtin_amdgcn_mfma_f32_16x16x32_bf16(pa[ks], vb, O[ht], 0, 0, 0);
      }
  }

  // epilogue: O /= l, write bf16
#pragma unroll
  for (int j = 0; j < 4; ++j) {
    float inv = 1.f / l_run[j];
    int row = b * Q_ + qt * 64 + w * 16 + lg * 4 + j;
#pragma unroll
    for (int ht = 0; ht < 4; ++ht)
      out[(size_t)row * E_ + h * 64 + ht * 16 + lr] = f2bf(O[ht][j] * inv);
  }
}

// ---------------- launch ----------------
extern "C" void kernel_launch(void* const* d_in, const int* in_sizes, int n_in,
                              void* d_out, int out_size, void* d_ws, size_t ws_size,
                              hipStream_t stream) {
  const float* query  = (const float*)d_in[0];
  const float* memory = (const float*)d_in[1];
  const float* bias   = (const float*)d_in[2];
  const float* Wq     = (const float*)d_in[3];
  const float* Wk     = (const float*)d_in[4];
  const float* Wv     = (const float*)d_in[5];
  const float* Wo     = (const float*)d_in[6];
  float* out = (float*)d_out;

  char* p = (char*)d_ws;
  u16* qb    = (u16*)p; p += (size_t)B_ * Q_ * E_ * 2;   // 8 MiB
  u16* mb    = (u16*)p; p += (size_t)B_ * K_ * E_ * 2;   // 16 MiB
  u16* wqt   = (u16*)p; p += (size_t)E_ * E_ * 2;        // 2 MiB
  u16* wkt   = (u16*)p; p += (size_t)E_ * E_ * 2;
  u16* wvt   = (u16*)p; p += (size_t)E_ * E_ * 2;
  u16* wot   = (u16*)p; p += (size_t)E_ * E_ * 2;
  u16* qproj = (u16*)p; p += (size_t)B_ * Q_ * E_ * 2;   // 8 MiB
  u16* kproj = (u16*)p; p += (size_t)B_ * K_ * E_ * 2;   // 16 MiB
  u16* vt    = (u16*)p; p += (size_t)B_ * K_ * E_ * 2;   // 16 MiB
  u16* attn  = (u16*)p; p += (size_t)B_ * Q_ * E_ * 2;   // 8 MiB  (total 80 MiB)

  cvt_f32_bf16<<<(B_ * Q_ * E_) / (8 * 256), 256, 0, stream>>>(query, qb, B_ * Q_ * E_);
  cvt_f32_bf16<<<(B_ * K_ * E_) / (8 * 256), 256, 0, stream>>>(memory, mb, B_ * K_ * E_);

  dim3 tg(16, 16);
  transpose_cvt<<<tg, 256, 0, stream>>>(Wq, wqt, E_, E_);
  transpose_cvt<<<tg, 256, 0, stream>>>(Wk, wkt, E_, E_);
  transpose_cvt<<<tg, 256, 0, stream>>>(Wv, wvt, E_, E_);
  transpose_cvt<<<tg, 256, 0, stream>>>(Wo, wot, E_, E_);

  dim3 g1(32, 8);   // 4096x1024
  dim3 g2(64, 8);   // 8192x1024
  gemm_bt<1><<<g1, 256, 0, stream>>>(qb, wqt, qproj, B_ * Q_, E_, E_);
  gemm_bt<1><<<g2, 256, 0, stream>>>(mb, wkt, kproj, B_ * K_, E_, E_);
  gemm_bt<2><<<g2, 256, 0, stream>>>(mb, wvt, vt,    B_ * K_, E_, E_);

  attn_kernel<<<B_ * H_ * (Q_ / 64), 256, 0, stream>>>(qproj, kproj, vt, bias, attn);

  gemm_bt<0><<<g1, 256, 0, stream>>>(attn, wot, out, B_ * Q_, E_, E_);
}

// Round 2
// 306.843 us; speedup vs baseline: 1.6144x; 1.6144x over previous
//
#include <hip/hip_runtime.h>
#include <cstdint>
#include <cstddef>

typedef unsigned short u16;
typedef __attribute__((ext_vector_type(8))) short bf16x8;   // 8 bf16 = 4 VGPRs
typedef __attribute__((ext_vector_type(4))) short bf16x4;   // 4 bf16 = 2 VGPRs
typedef __attribute__((ext_vector_type(4))) float f32x4;

#define B_  4
#define Q_  1024
#define K_  2048
#define E_  1024
#define H_  16
#define HD_ 64

__device__ inline u16 f2bf(float f) {
  union { float f; uint32_t u; } x; x.f = f;
  return (u16)((x.u + 0x7fffu + ((x.u >> 16) & 1u)) >> 16);  // RNE
}

__device__ inline void gload16(const u16* g, u16* l) {
  __builtin_amdgcn_global_load_lds((const __attribute__((address_space(1))) void*)g,
                                   (__attribute__((address_space(3))) void*)l, 16, 0, 0);
}

// ---------------- f32 -> bf16 elementwise convert ----------------
__global__ __launch_bounds__(256) void cvt_f32_bf16(const float* __restrict__ in,
                                                    u16* __restrict__ out, int n) {
  int i = (blockIdx.x * 256 + threadIdx.x) * 8;
  if (i + 7 < n) {
    float4 a = *reinterpret_cast<const float4*>(in + i);
    float4 b = *reinterpret_cast<const float4*>(in + i + 4);
    union { u16 u[8]; uint4 v; } r;
    r.u[0] = f2bf(a.x); r.u[1] = f2bf(a.y); r.u[2] = f2bf(a.z); r.u[3] = f2bf(a.w);
    r.u[4] = f2bf(b.x); r.u[5] = f2bf(b.y); r.u[6] = f2bf(b.z); r.u[7] = f2bf(b.w);
    *reinterpret_cast<uint4*>(out + i) = r.v;
  }
}

// ---------------- W[K][N] f32 -> Wt[N][K] bf16 (LDS tiled) ----------------
__global__ __launch_bounds__(256) void transpose_cvt(const float* __restrict__ W,
                                                     u16* __restrict__ Wt, int Kc, int N) {
  __shared__ float t[64][65];
  int k0 = blockIdx.x * 64, n0 = blockIdx.y * 64;
  int r = threadIdx.x >> 6, c = threadIdx.x & 63;
#pragma unroll
  for (int i = 0; i < 16; ++i)
    t[r + i * 4][c] = W[(size_t)(k0 + r + i * 4) * N + n0 + c];
  __syncthreads();
#pragma unroll
  for (int i = 0; i < 16; ++i)
    Wt[(size_t)(n0 + r + i * 4) * Kc + k0 + c] = f2bf(t[c][r + i * 4]);
}

// ---------------- bf16 GEMM: C[M,N] = A[M,K] * Bt[N,K]^T (m97-style) ----------------
// MODE 0: C f32 row-major. MODE 1: C bf16 row-major. MODE 3: C bf16 * 0.125.
// MODE 2: A=WvT[e][m], Bt=mb[n][m]; C[e][n] written to
//         vt[((n>>11)*16 + (e>>6))*64 + (e&63)][n&2047]   (coalesced along n)
template <int MODE>
__global__ __launch_bounds__(256) void gemm_bt(const u16* __restrict__ A,
                                               const u16* __restrict__ Bt,
                                               void* __restrict__ C,
                                               int M, int N, int Kc) {
  __shared__ u16 As[128 * 32];
  __shared__ u16 Bs[128 * 32];
  const int tid = threadIdx.x;
  const int w = tid >> 6, l = tid & 63;
  const int wr = w >> 1, wc = w & 1;
  const int lr = l & 15, lg = l >> 4;
  const int m0 = blockIdx.x * 128, n0 = blockIdx.y * 128;
  const int e = w * 1024 + l * 8;          // element base of this lane's first 16B chunk
  const int row0 = e >> 5, col0 = e & 31;  // 32 elem per LDS row

  f32x4 acc[4][4];
#pragma unroll
  for (int mt = 0; mt < 4; ++mt)
#pragma unroll
    for (int nt = 0; nt < 4; ++nt)
      acc[mt][nt] = (f32x4){0.f, 0.f, 0.f, 0.f};

  for (int k0 = 0; k0 < Kc; k0 += 32) {
    __syncthreads();   // prior iteration's LDS reads done
    gload16(A  + (size_t)(m0 + row0) * Kc + k0 + col0, &As[e]);
    gload16(Bt + (size_t)(n0 + row0) * Kc + k0 + col0, &Bs[e]);
    gload16(A  + (size_t)(m0 + row0 + 16) * Kc + k0 + col0, &As[e + 512]);
    gload16(Bt + (size_t)(n0 + row0 + 16) * Kc + k0 + col0, &Bs[e + 512]);
    __syncthreads();   // drains vmcnt -> tile resident

    bf16x8 a[4], b[4];
#pragma unroll
    for (int mt = 0; mt < 4; ++mt)
      a[mt] = *reinterpret_cast<const bf16x8*>(&As[(wr * 64 + mt * 16 + lr) * 32 + lg * 8]);
#pragma unroll
    for (int nt = 0; nt < 4; ++nt)
      b[nt] = *reinterpret_cast<const bf16x8*>(&Bs[(wc * 64 + nt * 16 + lr) * 32 + lg * 8]);
#pragma unroll
    for (int mt = 0; mt < 4; ++mt)
#pragma unroll
      for (int nt = 0; nt < 4; ++nt)
        acc[mt][nt] = __builtin_amdgcn_mfma_f32_16x16x32_bf16(a[mt], b[nt], acc[mt][nt], 0, 0, 0);
  }

#pragma unroll
  for (int mt = 0; mt < 4; ++mt) {
#pragma unroll
    for (int nt = 0; nt < 4; ++nt) {
      int col = n0 + wc * 64 + nt * 16 + lr;
#pragma unroll
      for (int j = 0; j < 4; ++j) {
        int row = m0 + wr * 64 + mt * 16 + lg * 4 + j;
        float v = acc[mt][nt][j];
        if (MODE == 0) {
          ((float*)C)[(size_t)row * N + col] = v;
        } else if (MODE == 1) {
          ((u16*)C)[(size_t)row * N + col] = f2bf(v);
        } else if (MODE == 3) {
          ((u16*)C)[(size_t)row * N + col] = f2bf(v * 0.125f);
        } else {
          ((u16*)C)[((size_t)((col >> 11) * 16 + (row >> 6)) * 64 + (row & 63)) * 2048 + (col & 2047)] = f2bf(v);
        }
      }
    }
  }
}

// ---------------- fused biased flash attention (swapped QK^T, in-register P) ----------------
// qp[b*Q+q][E] bf16 (pre-scaled by 1/8), kp[b*K+kk][E] bf16, vT[(b*H+h)*HD+hd][K] bf16,
// bias[b][K] f32 -> out attn[b*Q+q][E] bf16
__global__ __launch_bounds__(256) void attn_kernel(const u16* __restrict__ qp,
                                                   const u16* __restrict__ kp,
                                                   const u16* __restrict__ vT,
                                                   const float* __restrict__ bias,
                                                   u16* __restrict__ out) {
  __shared__ u16 q_lds[64 * 64];
  __shared__ u16 k_lds[64 * 64];
  __shared__ u16 v_lds[64 * 64];

  const int blk = blockIdx.x;
  const int qt = blk & 15, h = (blk >> 4) & 15, b = blk >> 8;
  const int tid = threadIdx.x;
  const int w = tid >> 6, l = tid & 63;
  const int lr = l & 15, lg = l >> 4;

  // stage Q tile [64 q][64 hd], XOR-swizzled rows
#pragma unroll
  for (int c = 0; c < 2; ++c) {
    int e = tid * 8 + c * 2048;
    int row = e >> 6, col = e & 63;
    int se = row * 64 + (col ^ ((row & 7) << 3));
    *reinterpret_cast<uint4*>(&q_lds[se]) =
        *reinterpret_cast<const uint4*>(qp + (size_t)(b * Q_ + qt * 64 + row) * E_ + h * 64 + col);
  }
  __syncthreads();
  // hoist Q fragments (B-operand): lane holds Q[q=w*16+lr][hd=ks*32+lg*8+..]
  bf16x8 qfrag[2];
#pragma unroll
  for (int ks = 0; ks < 2; ++ks) {
    int row = w * 16 + lr, col = ks * 32 + lg * 8;
    qfrag[ks] = *reinterpret_cast<const bf16x8*>(&q_lds[row * 64 + (col ^ ((row & 7) << 3))]);
  }

  f32x4 O[4];
#pragma unroll
  for (int ht = 0; ht < 4; ++ht) O[ht] = (f32x4){0.f, 0.f, 0.f, 0.f};
  float m_run = -1e30f, l_run = 0.f;
  const float* bias_b = bias + (size_t)b * K_;

  for (int kk0 = 0; kk0 < K_; kk0 += 64) {
    // reg-stage K tile [64 kk][64 hd] and V^T tile [64 hd][64 kk]
    uint4 kv[2], vv[2];
#pragma unroll
    for (int c = 0; c < 2; ++c) {
      int e = tid * 8 + c * 2048;
      int row = e >> 6, col = e & 63;
      kv[c] = *reinterpret_cast<const uint4*>(kp + (size_t)(b * K_ + kk0 + row) * E_ + h * 64 + col);
      vv[c] = *reinterpret_cast<const uint4*>(vT + (size_t)((b * H_ + h) * HD_ + row) * K_ + kk0 + col);
    }
    __syncthreads();   // prior iteration's MFMA reads done
#pragma unroll
    for (int c = 0; c < 2; ++c) {
      int e = tid * 8 + c * 2048;
      int row = e >> 6, col = e & 63;
      int se = row * 64 + (col ^ ((row & 7) << 3));
      *reinterpret_cast<uint4*>(&k_lds[se]) = kv[c];
      *reinterpret_cast<uint4*>(&v_lds[se]) = vv[c];
    }
    __syncthreads();

    // swapped QK^T: S^T[ct], lane holds S^T[k=ct*16+lg*4+j][q=w*16+lr]
    f32x4 S[4];
#pragma unroll
    for (int ct = 0; ct < 4; ++ct) {
      f32x4 s = (f32x4){0.f, 0.f, 0.f, 0.f};
#pragma unroll
      for (int ks = 0; ks < 2; ++ks) {
        int row = ct * 16 + lr, col = ks * 32 + lg * 8;
        bf16x8 kb = *reinterpret_cast<const bf16x8*>(&k_lds[row * 64 + (col ^ ((row & 7) << 3))]);
        s = __builtin_amdgcn_mfma_f32_16x16x32_bf16(kb, qfrag[ks], s, 0, 0, 0);
      }
      float4 bv = *reinterpret_cast<const float4*>(&bias_b[kk0 + ct * 16 + lg * 4]);
      S[ct][0] = s[0] + bv.x; S[ct][1] = s[1] + bv.y;
      S[ct][2] = s[2] + bv.z; S[ct][3] = s[3] + bv.w;
    }

    // per-lane softmax for q-row lr (4-lane lg-group shares the row)
    float tmax = -1e30f;
#pragma unroll
    for (int ct = 0; ct < 4; ++ct)
#pragma unroll
      for (int j = 0; j < 4; ++j) tmax = fmaxf(tmax, S[ct][j]);
    tmax = fmaxf(tmax, __shfl_xor(tmax, 16, 64));
    tmax = fmaxf(tmax, __shfl_xor(tmax, 32, 64));
    float m_new = fmaxf(m_run, tmax);
    float mf = __expf(m_run - m_new);
    m_run = m_new;

    float psum = 0.f;
    bf16x4 pf[4];
#pragma unroll
    for (int ct = 0; ct < 4; ++ct)
#pragma unroll
      for (int j = 0; j < 4; ++j) {
        float p = __expf(S[ct][j] - m_new);
        psum += p;
        pf[ct][j] = (short)f2bf(p);
      }
    psum += __shfl_xor(psum, 16, 64);
    psum += __shfl_xor(psum, 32, 64);
    l_run = l_run * mf + psum;

    // O rows are q=lg*4+j -> fetch that row's mf from the lane with lr==row
    float mfj[4];
#pragma unroll
    for (int j = 0; j < 4; ++j) mfj[j] = __shfl(mf, (l & 48) | (lg * 4 + j), 64);
#pragma unroll
    for (int ht = 0; ht < 4; ++ht)
#pragma unroll
      for (int j = 0; j < 4; ++j) O[ht][j] *= mfj[j];

    // PV: P is already the 16x16x16 A-fragment; V^T b64 frags from LDS
#pragma unroll
    for (int ct = 0; ct < 4; ++ct)
#pragma unroll
      for (int ht = 0; ht < 4; ++ht) {
        int row = ht * 16 + lr, col = ct * 16 + lg * 4;
        bf16x4 vb = *reinterpret_cast<const bf16x4*>(&v_lds[row * 64 + (col ^ ((row & 7) << 3))]);
        O[ht] = __builtin_amdgcn_mfma_f32_16x16x16bf16_1k(pf[ct], vb, O[ht], 0, 0, 0);
      }
  }

  // epilogue: O[q=lg*4+j][hd=ht*16+lr] /= l(q)
  float inv = 1.f / l_run;
  float invj[4];
#pragma unroll
  for (int j = 0; j < 4; ++j) invj[j] = __shfl(inv, (l & 48) | (lg * 4 + j), 64);
#pragma unroll
  for (int j = 0; j < 4; ++j) {
    int row = b * Q_ + qt * 64 + w * 16 + lg * 4 + j;
#pragma unroll
    for (int ht = 0; ht < 4; ++ht)
      out[(size_t)row * E_ + h * 64 + ht * 16 + lr] = f2bf(O[ht][j] * invj[j]);
  }
}

// ---------------- launch ----------------
extern "C" void kernel_launch(void* const* d_in, const int* in_sizes, int n_in,
                              void* d_out, int out_size, void* d_ws, size_t ws_size,
                              hipStream_t stream) {
  const float* query  = (const float*)d_in[0];
  const float* memory = (const float*)d_in[1];
  const float* bias   = (const float*)d_in[2];
  const float* Wq     = (const float*)d_in[3];
  const float* Wk     = (const float*)d_in[4];
  const float* Wv     = (const float*)d_in[5];
  const float* Wo     = (const float*)d_in[6];
  float* out = (float*)d_out;

  char* p = (char*)d_ws;
  u16* qb    = (u16*)p; p += (size_t)B_ * Q_ * E_ * 2;   // 8 MiB
  u16* mb    = (u16*)p; p += (size_t)B_ * K_ * E_ * 2;   // 16 MiB
  u16* wqt   = (u16*)p; p += (size_t)E_ * E_ * 2;        // 2 MiB
  u16* wkt   = (u16*)p; p += (size_t)E_ * E_ * 2;
  u16* wvt   = (u16*)p; p += (size_t)E_ * E_ * 2;
  u16* wot   = (u16*)p; p += (size_t)E_ * E_ * 2;
  u16* qproj = (u16*)p; p += (size_t)B_ * Q_ * E_ * 2;   // 8 MiB
  u16* kproj = (u16*)p; p += (size_t)B_ * K_ * E_ * 2;   // 16 MiB
  u16* vt    = (u16*)p; p += (size_t)B_ * K_ * E_ * 2;   // 16 MiB
  u16* attn  = (u16*)p; p += (size_t)B_ * Q_ * E_ * 2;   // 8 MiB  (total 80 MiB)

  cvt_f32_bf16<<<(B_ * Q_ * E_) / (8 * 256), 256, 0, stream>>>(query, qb, B_ * Q_ * E_);
  cvt_f32_bf16<<<(B_ * K_ * E_) / (8 * 256), 256, 0, stream>>>(memory, mb, B_ * K_ * E_);

  dim3 tg(16, 16);
  transpose_cvt<<<tg, 256, 0, stream>>>(Wq, wqt, E_, E_);
  transpose_cvt<<<tg, 256, 0, stream>>>(Wk, wkt, E_, E_);
  transpose_cvt<<<tg, 256, 0, stream>>>(Wv, wvt, E_, E_);
  transpose_cvt<<<tg, 256, 0, stream>>>(Wo, wot, E_, E_);

  gemm_bt<3><<<dim3(32, 8), 256, 0, stream>>>(qb, wqt, qproj, B_ * Q_, E_, E_);   // q-proj *0.125
  gemm_bt<1><<<dim3(64, 8), 256, 0, stream>>>(mb, wkt, kproj, B_ * K_, E_, E_);   // k-proj
  gemm_bt<2><<<dim3(8, 64), 256, 0, stream>>>(wvt, mb, vt, E_, B_ * K_, E_);      // v-proj -> vT

  attn_kernel<<<B_ * H_ * (Q_ / 64), 256, 0, stream>>>(qproj, kproj, vt, bias, attn);

  gemm_bt<0><<<dim3(32, 8), 256, 0, stream>>>(attn, wot, out, B_ * Q_, E_, E_);
}

// Round 3
// 275.560 us; speedup vs baseline: 1.7976x; 1.1135x over previous
//
#include <hip/hip_runtime.h>
#include <cstdint>
#include <cstddef>

typedef unsigned short u16;
typedef __attribute__((ext_vector_type(8))) short bf16x8;   // 8 bf16 = 4 VGPRs
typedef __attribute__((ext_vector_type(4))) short bf16x4;   // 4 bf16 = 2 VGPRs
typedef __attribute__((ext_vector_type(4))) float f32x4;

#define B_  4
#define Q_  1024
#define K_  2048
#define E_  1024
#define H_  16
#define HD_ 64

__device__ inline u16 f2bf(float f) {
  union { float f; uint32_t u; } x; x.f = f;
  return (u16)((x.u + 0x7fffu + ((x.u >> 16) & 1u)) >> 16);  // RNE
}

__device__ inline void gload16(const u16* g, u16* l) {
  __builtin_amdgcn_global_load_lds((const __attribute__((address_space(1))) void*)g,
                                   (__attribute__((address_space(3))) void*)l, 16, 0, 0);
}

// ---------------- f32 -> bf16 elementwise convert ----------------
__global__ __launch_bounds__(256) void cvt_f32_bf16(const float* __restrict__ in,
                                                    u16* __restrict__ out, int n) {
  int i = (blockIdx.x * 256 + threadIdx.x) * 8;
  if (i + 7 < n) {
    float4 a = *reinterpret_cast<const float4*>(in + i);
    float4 b = *reinterpret_cast<const float4*>(in + i + 4);
    union { u16 u[8]; uint4 v; } r;
    r.u[0] = f2bf(a.x); r.u[1] = f2bf(a.y); r.u[2] = f2bf(a.z); r.u[3] = f2bf(a.w);
    r.u[4] = f2bf(b.x); r.u[5] = f2bf(b.y); r.u[6] = f2bf(b.z); r.u[7] = f2bf(b.w);
    *reinterpret_cast<uint4*>(out + i) = r.v;
  }
}

// ---------------- W[K][N] f32 -> Wt[N][K] bf16 (LDS tiled) ----------------
__global__ __launch_bounds__(256) void transpose_cvt(const float* __restrict__ W,
                                                     u16* __restrict__ Wt, int Kc, int N) {
  __shared__ float t[64][65];
  int k0 = blockIdx.x * 64, n0 = blockIdx.y * 64;
  int r = threadIdx.x >> 6, c = threadIdx.x & 63;
#pragma unroll
  for (int i = 0; i < 16; ++i)
    t[r + i * 4][c] = W[(size_t)(k0 + r + i * 4) * N + n0 + c];
  __syncthreads();
#pragma unroll
  for (int i = 0; i < 16; ++i)
    Wt[(size_t)(n0 + r + i * 4) * Kc + k0 + c] = f2bf(t[c][r + i * 4]);
}

// ---------------- bf16 GEMM: C[M,N] = A[M,K] * Bt[N,K]^T (m97-style) ----------------
// MODE 0: C f32 row-major. MODE 1: C bf16 row-major. MODE 3: C bf16 * 0.125.
// MODE 2: A=WvT[e][m], Bt=mb[n][m]; C[e][n] written to
//         vt[((n>>11)*16 + (e>>6))*64 + (e&63)][n&2047]   (coalesced along n)
template <int MODE>
__global__ __launch_bounds__(256) void gemm_bt(const u16* __restrict__ A,
                                               const u16* __restrict__ Bt,
                                               void* __restrict__ C,
                                               int M, int N, int Kc) {
  __shared__ u16 As[128 * 32];
  __shared__ u16 Bs[128 * 32];
  const int tid = threadIdx.x;
  const int w = tid >> 6, l = tid & 63;
  const int wr = w >> 1, wc = w & 1;
  const int lr = l & 15, lg = l >> 4;
  const int m0 = blockIdx.x * 128, n0 = blockIdx.y * 128;
  const int e = w * 1024 + l * 8;          // element base of this lane's first 16B chunk
  const int row0 = e >> 5, col0 = e & 31;  // 32 elem per LDS row

  f32x4 acc[4][4];
#pragma unroll
  for (int mt = 0; mt < 4; ++mt)
#pragma unroll
    for (int nt = 0; nt < 4; ++nt)
      acc[mt][nt] = (f32x4){0.f, 0.f, 0.f, 0.f};

  for (int k0 = 0; k0 < Kc; k0 += 32) {
    __syncthreads();   // prior iteration's LDS reads done
    gload16(A  + (size_t)(m0 + row0) * Kc + k0 + col0, &As[e]);
    gload16(Bt + (size_t)(n0 + row0) * Kc + k0 + col0, &Bs[e]);
    gload16(A  + (size_t)(m0 + row0 + 16) * Kc + k0 + col0, &As[e + 512]);
    gload16(Bt + (size_t)(n0 + row0 + 16) * Kc + k0 + col0, &Bs[e + 512]);
    __syncthreads();   // drains vmcnt -> tile resident

    bf16x8 a[4], b[4];
#pragma unroll
    for (int mt = 0; mt < 4; ++mt)
      a[mt] = *reinterpret_cast<const bf16x8*>(&As[(wr * 64 + mt * 16 + lr) * 32 + lg * 8]);
#pragma unroll
    for (int nt = 0; nt < 4; ++nt)
      b[nt] = *reinterpret_cast<const bf16x8*>(&Bs[(wc * 64 + nt * 16 + lr) * 32 + lg * 8]);
#pragma unroll
    for (int mt = 0; mt < 4; ++mt)
#pragma unroll
      for (int nt = 0; nt < 4; ++nt)
        acc[mt][nt] = __builtin_amdgcn_mfma_f32_16x16x32_bf16(a[mt], b[nt], acc[mt][nt], 0, 0, 0);
  }

#pragma unroll
  for (int mt = 0; mt < 4; ++mt) {
#pragma unroll
    for (int nt = 0; nt < 4; ++nt) {
      int col = n0 + wc * 64 + nt * 16 + lr;
#pragma unroll
      for (int j = 0; j < 4; ++j) {
        int row = m0 + wr * 64 + mt * 16 + lg * 4 + j;
        float v = acc[mt][nt][j];
        if (MODE == 0) {
          ((float*)C)[(size_t)row * N + col] = v;
        } else if (MODE == 1) {
          ((u16*)C)[(size_t)row * N + col] = f2bf(v);
        } else if (MODE == 3) {
          ((u16*)C)[(size_t)row * N + col] = f2bf(v * 0.125f);
        } else {
          ((u16*)C)[((size_t)((col >> 11) * 16 + (row >> 6)) * 64 + (row & 63)) * 2048 + (col & 2047)] = f2bf(v);
        }
      }
    }
  }
}

// ---------------- fused biased flash attention ----------------
// QBLK=128 (4 waves x 32 q-rows), KVBLK=64, swapped QK^T, in-register P,
// head-pinned XCD mapping, async-staged K/V.
// qp[b*Q+q][E] bf16 (pre-scaled 1/8), kp[b*K+kk][E] bf16, vT[(b*H+h)*HD+hd][K] bf16,
// bias[b][K] f32 -> attn[b*Q+q][E] bf16
__global__ __launch_bounds__(256) void attn_kernel(const u16* __restrict__ qp,
                                                   const u16* __restrict__ kp,
                                                   const u16* __restrict__ vT,
                                                   const float* __restrict__ bias,
                                                   u16* __restrict__ out) {
  __shared__ u16 k_lds[64 * 64];
  __shared__ u16 v_lds[64 * 64];

  const int blk = blockIdx.x;
  const int hg = blk & 63, qt = blk >> 6;     // blk%8 == head%8 -> head pinned to XCD
  const int b = hg >> 4, h = hg & 15;
  const int tid = threadIdx.x;
  const int w = tid >> 6, l = tid & 63;
  const int lr = l & 15, lg = l >> 4;

  // Q fragments straight from global (B-operand): lane holds Q[q=qt*128+w*32+qb*16+lr][hd]
  bf16x8 qfrag[2][2];  // [ks][qb]
#pragma unroll
  for (int qb = 0; qb < 2; ++qb)
#pragma unroll
    for (int ks = 0; ks < 2; ++ks)
      qfrag[ks][qb] = *reinterpret_cast<const bf16x8*>(
          qp + (size_t)(b * Q_ + qt * 128 + w * 32 + qb * 16 + lr) * E_ + h * 64 + ks * 32 + lg * 8);

  f32x4 O[4][2];
#pragma unroll
  for (int ht = 0; ht < 4; ++ht)
#pragma unroll
    for (int qb = 0; qb < 2; ++qb) O[ht][qb] = (f32x4){0.f, 0.f, 0.f, 0.f};
  float m_run[2] = {-1e30f, -1e30f}, l_run[2] = {0.f, 0.f};
  const float* bias_b = bias + (size_t)b * K_;
  const u16* kbase = kp + (size_t)b * K_ * E_ + h * 64;
  const u16* vbase = vT + (size_t)(b * H_ + h) * HD_ * K_;

  // prologue: stage tile 0 into regs
  uint4 kv[2], vv[2];
#pragma unroll
  for (int c = 0; c < 2; ++c) {
    int e = tid * 8 + c * 2048;
    int row = e >> 6, col = e & 63;
    kv[c] = *reinterpret_cast<const uint4*>(kbase + (size_t)row * E_ + col);
    vv[c] = *reinterpret_cast<const uint4*>(vbase + (size_t)row * K_ + col);
  }

  for (int t = 0; t < K_ / 64; ++t) {
    __syncthreads();   // prior tile's LDS reads done
#pragma unroll
    for (int c = 0; c < 2; ++c) {
      int e = tid * 8 + c * 2048;
      int row = e >> 6, col = e & 63;
      int se = row * 64 + (col ^ ((row & 7) << 3));
      *reinterpret_cast<uint4*>(&k_lds[se]) = kv[c];
      *reinterpret_cast<uint4*>(&v_lds[se]) = vv[c];
    }
    __syncthreads();

    // async-STAGE: issue next tile's loads before compute (HBM/L2 latency hides under MFMA)
    if (t + 1 < K_ / 64) {
      int kk0 = (t + 1) * 64;
#pragma unroll
      for (int c = 0; c < 2; ++c) {
        int e = tid * 8 + c * 2048;
        int row = e >> 6, col = e & 63;
        kv[c] = *reinterpret_cast<const uint4*>(kbase + (size_t)(kk0 + row) * E_ + col);
        vv[c] = *reinterpret_cast<const uint4*>(vbase + (size_t)row * K_ + kk0 + col);
      }
    }

    // swapped QK^T: lane holds S^T[k=ct*16+lg*4+j][q=w*32+qb*16+lr]
    f32x4 S[4][2];
#pragma unroll
    for (int ct = 0; ct < 4; ++ct) {
      int row = ct * 16 + lr;
      bf16x8 kb0 = *reinterpret_cast<const bf16x8*>(&k_lds[row * 64 + ((lg * 8) ^ ((row & 7) << 3))]);
      bf16x8 kb1 = *reinterpret_cast<const bf16x8*>(&k_lds[row * 64 + ((32 + lg * 8) ^ ((row & 7) << 3))]);
      float4 bv = *reinterpret_cast<const float4*>(&bias_b[t * 64 + ct * 16 + lg * 4]);
#pragma unroll
      for (int qb = 0; qb < 2; ++qb) {
        f32x4 s = (f32x4){0.f, 0.f, 0.f, 0.f};
        s = __builtin_amdgcn_mfma_f32_16x16x32_bf16(kb0, qfrag[0][qb], s, 0, 0, 0);
        s = __builtin_amdgcn_mfma_f32_16x16x32_bf16(kb1, qfrag[1][qb], s, 0, 0, 0);
        S[ct][qb][0] = s[0] + bv.x; S[ct][qb][1] = s[1] + bv.y;
        S[ct][qb][2] = s[2] + bv.z; S[ct][qb][3] = s[3] + bv.w;
      }
    }

    // per-lane online softmax (q-row = qb*16+lr within wave; lg-groups share row)
    bf16x4 pf[4][2];
#pragma unroll
    for (int qb = 0; qb < 2; ++qb) {
      float tmax = -1e30f;
#pragma unroll
      for (int ct = 0; ct < 4; ++ct)
#pragma unroll
        for (int j = 0; j < 4; ++j) tmax = fmaxf(tmax, S[ct][qb][j]);
      tmax = fmaxf(tmax, __shfl_xor(tmax, 16, 64));
      tmax = fmaxf(tmax, __shfl_xor(tmax, 32, 64));
      float m_new = fmaxf(m_run[qb], tmax);
      float mf = __expf(m_run[qb] - m_new);
      m_run[qb] = m_new;

      float psum = 0.f;
#pragma unroll
      for (int ct = 0; ct < 4; ++ct)
#pragma unroll
        for (int j = 0; j < 4; ++j) {
          float p = __expf(S[ct][qb][j] - m_new);
          psum += p;
          pf[ct][qb][j] = (short)f2bf(p);
        }
      psum += __shfl_xor(psum, 16, 64);
      psum += __shfl_xor(psum, 32, 64);
      l_run[qb] = l_run[qb] * mf + psum;

      float mfj[4];
#pragma unroll
      for (int j = 0; j < 4; ++j) mfj[j] = __shfl(mf, (l & 48) | (lg * 4 + j), 64);
#pragma unroll
      for (int ht = 0; ht < 4; ++ht)
#pragma unroll
        for (int j = 0; j < 4; ++j) O[ht][qb][j] *= mfj[j];
    }

    // PV: P already in A-fragment layout of 16x16x16; V^T b64 frags shared across qb
#pragma unroll
    for (int ct = 0; ct < 4; ++ct)
#pragma unroll
      for (int ht = 0; ht < 4; ++ht) {
        int row = ht * 16 + lr;
        bf16x4 vb = *reinterpret_cast<const bf16x4*>(
            &v_lds[row * 64 + ((ct * 16 + lg * 4) ^ ((row & 7) << 3))]);
#pragma unroll
        for (int qb = 0; qb < 2; ++qb)
          O[ht][qb] = __builtin_amdgcn_mfma_f32_16x16x16bf16_1k(pf[ct][qb], vb, O[ht][qb], 0, 0, 0);
      }
  }

  // epilogue: O[q=qb*16+lg*4+j][hd=ht*16+lr] /= l(q)
#pragma unroll
  for (int qb = 0; qb < 2; ++qb) {
    float inv = 1.f / l_run[qb];
    float invj[4];
#pragma unroll
    for (int j = 0; j < 4; ++j) invj[j] = __shfl(inv, (l & 48) | (lg * 4 + j), 64);
#pragma unroll
    for (int j = 0; j < 4; ++j) {
      int row = b * Q_ + qt * 128 + w * 32 + qb * 16 + lg * 4 + j;
#pragma unroll
      for (int ht = 0; ht < 4; ++ht)
        out[(size_t)row * E_ + h * 64 + ht * 16 + lr] = f2bf(O[ht][qb][j] * invj[j]);
    }
  }
}

// ---------------- launch ----------------
extern "C" void kernel_launch(void* const* d_in, const int* in_sizes, int n_in,
                              void* d_out, int out_size, void* d_ws, size_t ws_size,
                              hipStream_t stream) {
  const float* query  = (const float*)d_in[0];
  const float* memory = (const float*)d_in[1];
  const float* bias   = (const float*)d_in[2];
  const float* Wq     = (const float*)d_in[3];
  const float* Wk     = (const float*)d_in[4];
  const float* Wv     = (const float*)d_in[5];
  const float* Wo     = (const float*)d_in[6];
  float* out = (float*)d_out;

  char* p = (char*)d_ws;
  u16* qb    = (u16*)p; p += (size_t)B_ * Q_ * E_ * 2;   // 8 MiB
  u16* mb    = (u16*)p; p += (size_t)B_ * K_ * E_ * 2;   // 16 MiB
  u16* wqt   = (u16*)p; p += (size_t)E_ * E_ * 2;        // 2 MiB
  u16* wkt   = (u16*)p; p += (size_t)E_ * E_ * 2;
  u16* wvt   = (u16*)p; p += (size_t)E_ * E_ * 2;
  u16* wot   = (u16*)p; p += (size_t)E_ * E_ * 2;
  u16* qproj = (u16*)p; p += (size_t)B_ * Q_ * E_ * 2;   // 8 MiB
  u16* kproj = (u16*)p; p += (size_t)B_ * K_ * E_ * 2;   // 16 MiB
  u16* vt    = (u16*)p; p += (size_t)B_ * K_ * E_ * 2;   // 16 MiB
  u16* attn  = (u16*)p; p += (size_t)B_ * Q_ * E_ * 2;   // 8 MiB  (total 80 MiB)

  cvt_f32_bf16<<<(B_ * Q_ * E_) / (8 * 256), 256, 0, stream>>>(query, qb, B_ * Q_ * E_);
  cvt_f32_bf16<<<(B_ * K_ * E_) / (8 * 256), 256, 0, stream>>>(memory, mb, B_ * K_ * E_);

  dim3 tg(16, 16);
  transpose_cvt<<<tg, 256, 0, stream>>>(Wq, wqt, E_, E_);
  transpose_cvt<<<tg, 256, 0, stream>>>(Wk, wkt, E_, E_);
  transpose_cvt<<<tg, 256, 0, stream>>>(Wv, wvt, E_, E_);
  transpose_cvt<<<tg, 256, 0, stream>>>(Wo, wot, E_, E_);

  gemm_bt<3><<<dim3(32, 8), 256, 0, stream>>>(qb, wqt, qproj, B_ * Q_, E_, E_);   // q-proj *0.125
  gemm_bt<1><<<dim3(64, 8), 256, 0, stream>>>(mb, wkt, kproj, B_ * K_, E_, E_);   // k-proj
  gemm_bt<2><<<dim3(8, 64), 256, 0, stream>>>(wvt, mb, vt, E_, B_ * K_, E_);      // v-proj -> vT

  attn_kernel<<<B_ * H_ * (Q_ / 128), 256, 0, stream>>>(qproj, kproj, vt, bias, attn);

  gemm_bt<0><<<dim3(32, 8), 256, 0, stream>>>(attn, wot, out, B_ * Q_, E_, E_);
}

// Round 4
// 216.400 us; speedup vs baseline: 2.2891x; 1.2734x over previous
//
#include <hip/hip_runtime.h>
#include <cstdint>
#include <cstddef>

typedef unsigned short u16;
typedef __attribute__((ext_vector_type(8))) short bf16x8;   // 8 bf16 = 4 VGPRs
typedef __attribute__((ext_vector_type(4))) short bf16x4;   // 4 bf16 = 2 VGPRs
typedef __attribute__((ext_vector_type(4))) float f32x4;

#define B_  4
#define Q_  1024
#define K_  2048
#define E_  1024
#define H_  16
#define HD_ 64
#define LOG2E 1.4426950408889634f

__device__ inline u16 f2bf(float f) {
  union { float f; uint32_t u; } x; x.f = f;
  return (u16)((x.u + 0x7fffu + ((x.u >> 16) & 1u)) >> 16);  // RNE
}

__device__ inline void gload16(const u16* g, u16* l) {
  __builtin_amdgcn_global_load_lds((const __attribute__((address_space(1))) void*)g,
                                   (__attribute__((address_space(3))) void*)l, 16, 0, 0);
}

// ---------------- f32 -> bf16 elementwise convert ----------------
__global__ __launch_bounds__(256) void cvt_f32_bf16(const float* __restrict__ in,
                                                    u16* __restrict__ out, int n) {
  int i = (blockIdx.x * 256 + threadIdx.x) * 8;
  if (i + 7 < n) {
    float4 a = *reinterpret_cast<const float4*>(in + i);
    float4 b = *reinterpret_cast<const float4*>(in + i + 4);
    union { u16 u[8]; uint4 v; } r;
    r.u[0] = f2bf(a.x); r.u[1] = f2bf(a.y); r.u[2] = f2bf(a.z); r.u[3] = f2bf(a.w);
    r.u[4] = f2bf(b.x); r.u[5] = f2bf(b.y); r.u[6] = f2bf(b.z); r.u[7] = f2bf(b.w);
    *reinterpret_cast<uint4*>(out + i) = r.v;
  }
}

// ---------------- bias * log2e ----------------
__global__ __launch_bounds__(256) void scale_bias(const float* __restrict__ in,
                                                  float* __restrict__ out, int n) {
  int i = blockIdx.x * 256 + threadIdx.x;
  if (i < n) out[i] = in[i] * LOG2E;
}

// ---------------- 4x fused W[1024][1024] f32 -> Wt bf16 transpose ----------------
__global__ __launch_bounds__(256) void transpose_cvt4(const float* W0, const float* W1,
                                                      const float* W2, const float* W3,
                                                      u16* T0, u16* T1, u16* T2, u16* T3) {
  __shared__ float t[64][65];
  const float* W; u16* T;
  switch (blockIdx.z) {
    case 0: W = W0; T = T0; break;
    case 1: W = W1; T = T1; break;
    case 2: W = W2; T = T2; break;
    default: W = W3; T = T3; break;
  }
  int k0 = blockIdx.x * 64, n0 = blockIdx.y * 64;
  int r = threadIdx.x >> 6, c = threadIdx.x & 63;
#pragma unroll
  for (int i = 0; i < 16; ++i)
    t[r + i * 4][c] = W[(size_t)(k0 + r + i * 4) * E_ + n0 + c];
  __syncthreads();
#pragma unroll
  for (int i = 0; i < 16; ++i)
    T[(size_t)(n0 + r + i * 4) * E_ + k0 + c] = f2bf(t[c][r + i * 4]);
}

// ---------------- bf16 GEMM: C[M,N] = A[M,K] * Bt[N,K]^T (m97-style) ----------------
// MODE 0: C f32 row-major. MODE 1: C bf16 row-major. MODE 3: C bf16 * 0.125*log2e.
// MODE 2: A=WvT[e][m], Bt=mb[n][m]; C[e][n] -> vt[((n>>11)*16+(e>>6))*64+(e&63)][n&2047]
template <int MODE>
__global__ __launch_bounds__(256) void gemm_bt(const u16* __restrict__ A,
                                               const u16* __restrict__ Bt,
                                               void* __restrict__ C,
                                               int M, int N, int Kc) {
  __shared__ u16 As[128 * 32];
  __shared__ u16 Bs[128 * 32];
  const int tid = threadIdx.x;
  const int w = tid >> 6, l = tid & 63;
  const int wr = w >> 1, wc = w & 1;
  const int lr = l & 15, lg = l >> 4;
  const int m0 = blockIdx.x * 128, n0 = blockIdx.y * 128;
  const int e = w * 1024 + l * 8;
  const int row0 = e >> 5, col0 = e & 31;

  f32x4 acc[4][4];
#pragma unroll
  for (int mt = 0; mt < 4; ++mt)
#pragma unroll
    for (int nt = 0; nt < 4; ++nt)
      acc[mt][nt] = (f32x4){0.f, 0.f, 0.f, 0.f};

  for (int k0 = 0; k0 < Kc; k0 += 32) {
    __syncthreads();
    gload16(A  + (size_t)(m0 + row0) * Kc + k0 + col0, &As[e]);
    gload16(Bt + (size_t)(n0 + row0) * Kc + k0 + col0, &Bs[e]);
    gload16(A  + (size_t)(m0 + row0 + 16) * Kc + k0 + col0, &As[e + 512]);
    gload16(Bt + (size_t)(n0 + row0 + 16) * Kc + k0 + col0, &Bs[e + 512]);
    __syncthreads();

    bf16x8 a[4], b[4];
#pragma unroll
    for (int mt = 0; mt < 4; ++mt)
      a[mt] = *reinterpret_cast<const bf16x8*>(&As[(wr * 64 + mt * 16 + lr) * 32 + lg * 8]);
#pragma unroll
    for (int nt = 0; nt < 4; ++nt)
      b[nt] = *reinterpret_cast<const bf16x8*>(&Bs[(wc * 64 + nt * 16 + lr) * 32 + lg * 8]);
#pragma unroll
    for (int mt = 0; mt < 4; ++mt)
#pragma unroll
      for (int nt = 0; nt < 4; ++nt)
        acc[mt][nt] = __builtin_amdgcn_mfma_f32_16x16x32_bf16(a[mt], b[nt], acc[mt][nt], 0, 0, 0);
  }

#pragma unroll
  for (int mt = 0; mt < 4; ++mt) {
#pragma unroll
    for (int nt = 0; nt < 4; ++nt) {
      int col = n0 + wc * 64 + nt * 16 + lr;
#pragma unroll
      for (int j = 0; j < 4; ++j) {
        int row = m0 + wr * 64 + mt * 16 + lg * 4 + j;
        float v = acc[mt][nt][j];
        if (MODE == 0) {
          ((float*)C)[(size_t)row * N + col] = v;
        } else if (MODE == 1) {
          ((u16*)C)[(size_t)row * N + col] = f2bf(v);
        } else if (MODE == 3) {
          ((u16*)C)[(size_t)row * N + col] = f2bf(v * (0.125f * LOG2E));
        } else {
          ((u16*)C)[((size_t)((col >> 11) * 16 + (row >> 6)) * 64 + (row & 63)) * 2048 + (col & 2047)] = f2bf(v);
        }
      }
    }
  }
}

// ---------------- fused biased flash attention ----------------
// QBLK=64 (4 waves x 16 q-rows), KVBLK=64, double-buffered LDS (1 barrier/iter),
// swapped QK^T, in-register P, head-pinned XCD mapping, exp2-domain softmax.
// qp bf16 (pre-scaled 0.125*log2e), kp bf16, vT bf16, bias2 f32 (pre-scaled log2e)
__global__ __launch_bounds__(256, 4) void attn_kernel(const u16* __restrict__ qp,
                                                      const u16* __restrict__ kp,
                                                      const u16* __restrict__ vT,
                                                      const float* __restrict__ bias2,
                                                      u16* __restrict__ out) {
  __shared__ u16 k_lds[2][64 * 64];
  __shared__ u16 v_lds[2][64 * 64];

  const int blk = blockIdx.x;
  const int hg = blk & 63, qt = blk >> 6;     // blk%8 == h%8 -> head pinned to XCD
  const int b = hg >> 4, h = hg & 15;
  const int tid = threadIdx.x;
  const int w = tid >> 6, l = tid & 63;
  const int lr = l & 15, lg = l >> 4;

  // Q fragments straight from global: lane holds Q[q=qt*64+w*16+lr][hd=ks*32+lg*8+..]
  bf16x8 qfrag[2];
#pragma unroll
  for (int ks = 0; ks < 2; ++ks)
    qfrag[ks] = *reinterpret_cast<const bf16x8*>(
        qp + (size_t)(b * Q_ + qt * 64 + w * 16 + lr) * E_ + h * 64 + ks * 32 + lg * 8);

  f32x4 O[4];
#pragma unroll
  for (int ht = 0; ht < 4; ++ht) O[ht] = (f32x4){0.f, 0.f, 0.f, 0.f};
  float m_run = -1e30f, l_run = 0.f;
  const float* bias_b = bias2 + (size_t)b * K_;
  const u16* kbase = kp + (size_t)b * K_ * E_ + h * 64;
  const u16* vbase = vT + (size_t)(b * H_ + h) * HD_ * K_;

  const int e0 = tid * 8, e1 = tid * 8 + 2048;
  const int r0 = e0 >> 6, c0 = e0 & 63;
  const int r1 = e1 >> 6, c1 = e1 & 63;
  const int s0 = r0 * 64 + (c0 ^ ((r0 & 7) << 3));
  const int s1 = r1 * 64 + (c1 ^ ((r1 & 7) << 3));

  // prologue: stage tile 0 -> buf0
  {
    uint4 k0v = *reinterpret_cast<const uint4*>(kbase + (size_t)r0 * E_ + c0);
    uint4 k1v = *reinterpret_cast<const uint4*>(kbase + (size_t)r1 * E_ + c1);
    uint4 v0v = *reinterpret_cast<const uint4*>(vbase + (size_t)r0 * K_ + c0);
    uint4 v1v = *reinterpret_cast<const uint4*>(vbase + (size_t)r1 * K_ + c1);
    *reinterpret_cast<uint4*>(&k_lds[0][s0]) = k0v;
    *reinterpret_cast<uint4*>(&k_lds[0][s1]) = k1v;
    *reinterpret_cast<uint4*>(&v_lds[0][s0]) = v0v;
    *reinterpret_cast<uint4*>(&v_lds[0][s1]) = v1v;
  }
  __syncthreads();

  const int NT = K_ / 64;
  for (int t = 0; t < NT; ++t) {
    const int cur = t & 1;
    // issue next tile's global loads early (latency hides under compute)
    uint4 kv0, kv1, vv0, vv1;
    if (t + 1 < NT) {
      int kk0 = (t + 1) * 64;
      kv0 = *reinterpret_cast<const uint4*>(kbase + (size_t)(kk0 + r0) * E_ + c0);
      kv1 = *reinterpret_cast<const uint4*>(kbase + (size_t)(kk0 + r1) * E_ + c1);
      vv0 = *reinterpret_cast<const uint4*>(vbase + (size_t)r0 * K_ + kk0 + c0);
      vv1 = *reinterpret_cast<const uint4*>(vbase + (size_t)r1 * K_ + kk0 + c1);
    }

    // swapped QK^T: lane holds S^T[k=ct*16+lg*4+j][q=w*16+lr] (log2 domain)
    f32x4 S[4];
    __builtin_amdgcn_s_setprio(1);
#pragma unroll
    for (int ct = 0; ct < 4; ++ct) {
      int row = ct * 16 + lr;
      bf16x8 kb0 = *reinterpret_cast<const bf16x8*>(&k_lds[cur][row * 64 + ((lg * 8) ^ ((row & 7) << 3))]);
      bf16x8 kb1 = *reinterpret_cast<const bf16x8*>(&k_lds[cur][row * 64 + ((32 + lg * 8) ^ ((row & 7) << 3))]);
      f32x4 s = (f32x4){0.f, 0.f, 0.f, 0.f};
      s = __builtin_amdgcn_mfma_f32_16x16x32_bf16(kb0, qfrag[0], s, 0, 0, 0);
      s = __builtin_amdgcn_mfma_f32_16x16x32_bf16(kb1, qfrag[1], s, 0, 0, 0);
      S[ct] = s;
    }
    __builtin_amdgcn_s_setprio(0);
#pragma unroll
    for (int ct = 0; ct < 4; ++ct) {
      float4 bv = *reinterpret_cast<const float4*>(&bias_b[t * 64 + ct * 16 + lg * 4]);
      S[ct][0] += bv.x; S[ct][1] += bv.y; S[ct][2] += bv.z; S[ct][3] += bv.w;
    }

    // per-lane online softmax for q-row lr (lg-groups share the row)
    float tmax = -1e30f;
#pragma unroll
    for (int ct = 0; ct < 4; ++ct)
#pragma unroll
      for (int j = 0; j < 4; ++j) tmax = fmaxf(tmax, S[ct][j]);
    tmax = fmaxf(tmax, __shfl_xor(tmax, 16, 64));
    tmax = fmaxf(tmax, __shfl_xor(tmax, 32, 64));
    float m_new = fmaxf(m_run, tmax);
    float mf = exp2f(m_run - m_new);
    m_run = m_new;

    float psum = 0.f;
    bf16x4 pf[4];
#pragma unroll
    for (int ct = 0; ct < 4; ++ct)
#pragma unroll
      for (int j = 0; j < 4; ++j) {
        float p = exp2f(S[ct][j] - m_new);
        psum += p;
        pf[ct][j] = (short)f2bf(p);
      }
    psum += __shfl_xor(psum, 16, 64);
    psum += __shfl_xor(psum, 32, 64);
    l_run = l_run * mf + psum;

    float mfj[4];
#pragma unroll
    for (int j = 0; j < 4; ++j) mfj[j] = __shfl(mf, (l & 48) | (lg * 4 + j), 64);
#pragma unroll
    for (int ht = 0; ht < 4; ++ht)
#pragma unroll
      for (int j = 0; j < 4; ++j) O[ht][j] *= mfj[j];

    // PV: P already in 16x16x16 A-fragment layout
    __builtin_amdgcn_s_setprio(1);
#pragma unroll
    for (int ct = 0; ct < 4; ++ct)
#pragma unroll
      for (int ht = 0; ht < 4; ++ht) {
        int row = ht * 16 + lr;
        bf16x4 vb = *reinterpret_cast<const bf16x4*>(
            &v_lds[cur][row * 64 + ((ct * 16 + lg * 4) ^ ((row & 7) << 3))]);
        O[ht] = __builtin_amdgcn_mfma_f32_16x16x16bf16_1k(pf[ct], vb, O[ht], 0, 0, 0);
      }
    __builtin_amdgcn_s_setprio(0);

    // write next tile into the other buffer (its previous readers finished last barrier)
    if (t + 1 < NT) {
      *reinterpret_cast<uint4*>(&k_lds[cur ^ 1][s0]) = kv0;
      *reinterpret_cast<uint4*>(&k_lds[cur ^ 1][s1]) = kv1;
      *reinterpret_cast<uint4*>(&v_lds[cur ^ 1][s0]) = vv0;
      *reinterpret_cast<uint4*>(&v_lds[cur ^ 1][s1]) = vv1;
    }
    __syncthreads();
  }

  // epilogue: O[q=lg*4+j][hd=ht*16+lr] /= l(q)
  float inv = 1.f / l_run;
  float invj[4];
#pragma unroll
  for (int j = 0; j < 4; ++j) invj[j] = __shfl(inv, (l & 48) | (lg * 4 + j), 64);
#pragma unroll
  for (int j = 0; j < 4; ++j) {
    int row = b * Q_ + qt * 64 + w * 16 + lg * 4 + j;
#pragma unroll
    for (int ht = 0; ht < 4; ++ht)
      out[(size_t)row * E_ + h * 64 + ht * 16 + lr] = f2bf(O[ht][j] * invj[j]);
  }
}

// ---------------- launch ----------------
extern "C" void kernel_launch(void* const* d_in, const int* in_sizes, int n_in,
                              void* d_out, int out_size, void* d_ws, size_t ws_size,
                              hipStream_t stream) {
  const float* query  = (const float*)d_in[0];
  const float* memory = (const float*)d_in[1];
  const float* bias   = (const float*)d_in[2];
  const float* Wq     = (const float*)d_in[3];
  const float* Wk     = (const float*)d_in[4];
  const float* Wv     = (const float*)d_in[5];
  const float* Wo     = (const float*)d_in[6];
  float* out = (float*)d_out;

  char* p = (char*)d_ws;
  u16* qb    = (u16*)p; p += (size_t)B_ * Q_ * E_ * 2;   // 8 MiB
  u16* mb    = (u16*)p; p += (size_t)B_ * K_ * E_ * 2;   // 16 MiB
  u16* wqt   = (u16*)p; p += (size_t)E_ * E_ * 2;        // 2 MiB
  u16* wkt   = (u16*)p; p += (size_t)E_ * E_ * 2;
  u16* wvt   = (u16*)p; p += (size_t)E_ * E_ * 2;
  u16* wot   = (u16*)p; p += (size_t)E_ * E_ * 2;
  u16* qproj = (u16*)p; p += (size_t)B_ * Q_ * E_ * 2;   // 8 MiB
  u16* kproj = (u16*)p; p += (size_t)B_ * K_ * E_ * 2;   // 16 MiB
  u16* vt    = (u16*)p; p += (size_t)B_ * K_ * E_ * 2;   // 16 MiB
  u16* attn  = (u16*)p; p += (size_t)B_ * Q_ * E_ * 2;   // 8 MiB
  float* bias2 = (float*)p; p += (size_t)B_ * K_ * 4;    // 32 KiB (total ~80 MiB)

  cvt_f32_bf16<<<(B_ * Q_ * E_) / (8 * 256), 256, 0, stream>>>(query, qb, B_ * Q_ * E_);
  cvt_f32_bf16<<<(B_ * K_ * E_) / (8 * 256), 256, 0, stream>>>(memory, mb, B_ * K_ * E_);
  scale_bias<<<(B_ * K_ + 255) / 256, 256, 0, stream>>>(bias, bias2, B_ * K_);

  transpose_cvt4<<<dim3(16, 16, 4), 256, 0, stream>>>(Wq, Wk, Wv, Wo, wqt, wkt, wvt, wot);

  gemm_bt<3><<<dim3(32, 8), 256, 0, stream>>>(qb, wqt, qproj, B_ * Q_, E_, E_);   // q-proj * 0.125*log2e
  gemm_bt<1><<<dim3(64, 8), 256, 0, stream>>>(mb, wkt, kproj, B_ * K_, E_, E_);   // k-proj
  gemm_bt<2><<<dim3(8, 64), 256, 0, stream>>>(wvt, mb, vt, E_, B_ * K_, E_);      // v-proj -> vT

  attn_kernel<<<B_ * H_ * (Q_ / 64), 256, 0, stream>>>(qproj, kproj, vt, bias2, attn);

  gemm_bt<0><<<dim3(32, 8), 256, 0, stream>>>(attn, wot, out, B_ * Q_, E_, E_);
}

// Round 5
// 204.869 us; speedup vs baseline: 2.4179x; 1.0563x over previous
//
#include <hip/hip_runtime.h>
#include <cstdint>
#include <cstddef>

typedef unsigned short u16;
typedef __attribute__((ext_vector_type(8))) short bf16x8;   // 8 bf16 = 4 VGPRs
typedef __attribute__((ext_vector_type(4))) short bf16x4;   // 4 bf16 = 2 VGPRs
typedef __attribute__((ext_vector_type(4))) float f32x4;

#define B_  4
#define Q_  1024
#define K_  2048
#define E_  1024
#define H_  16
#define HD_ 64
#define LOG2E 1.4426950408889634f
#define DEFER_THR 12.0f

__device__ inline u16 f2bf(float f) {
  union { float f; uint32_t u; } x; x.f = f;
  return (u16)((x.u + 0x7fffu + ((x.u >> 16) & 1u)) >> 16);  // RNE
}

// native bf16 convert — compiler emits packed v_cvt (m240: casts compile well)
__device__ inline short bfc(float f) {
  __bf16 h = (__bf16)f;
  return __builtin_bit_cast(short, h);
}

__device__ inline void gload16(const u16* g, u16* l) {
  __builtin_amdgcn_global_load_lds((const __attribute__((address_space(1))) void*)g,
                                   (__attribute__((address_space(3))) void*)l, 16, 0, 0);
}

// ---------------- fused prep: query->bf16, memory->bf16, bias*log2e ----------------
#define NQ8 (B_ * Q_ * E_ / 8)          // 524288
#define NM8 (B_ * K_ * E_ / 8)          // 1048576
#define NBI (B_ * K_)                   // 8192
__global__ __launch_bounds__(256) void prep_kernel(const float* __restrict__ query,
                                                   const float* __restrict__ memory,
                                                   const float* __restrict__ bias,
                                                   u16* __restrict__ qb,
                                                   u16* __restrict__ mb,
                                                   float* __restrict__ bias2) {
  int i = blockIdx.x * 256 + threadIdx.x;
  const float* src;
  u16* dst;
  if (i < NQ8) {
    src = query + (size_t)i * 8; dst = qb + (size_t)i * 8;
  } else if (i < NQ8 + NM8) {
    int j = i - NQ8;
    src = memory + (size_t)j * 8; dst = mb + (size_t)j * 8;
  } else {
    int j = i - (NQ8 + NM8);
    if (j < NBI) bias2[j] = bias[j] * LOG2E;
    return;
  }
  float4 a = *reinterpret_cast<const float4*>(src);
  float4 b = *reinterpret_cast<const float4*>(src + 4);
  union { u16 u[8]; uint4 v; } r;
  r.u[0] = f2bf(a.x); r.u[1] = f2bf(a.y); r.u[2] = f2bf(a.z); r.u[3] = f2bf(a.w);
  r.u[4] = f2bf(b.x); r.u[5] = f2bf(b.y); r.u[6] = f2bf(b.z); r.u[7] = f2bf(b.w);
  *reinterpret_cast<uint4*>(dst) = r.v;
}

// ---------------- 4x fused W[1024][1024] f32 -> Wt bf16 transpose ----------------
__global__ __launch_bounds__(256) void transpose_cvt4(const float* W0, const float* W1,
                                                      const float* W2, const float* W3,
                                                      u16* T0, u16* T1, u16* T2, u16* T3) {
  __shared__ float t[64][65];
  const float* W; u16* T;
  switch (blockIdx.z) {
    case 0: W = W0; T = T0; break;
    case 1: W = W1; T = T1; break;
    case 2: W = W2; T = T2; break;
    default: W = W3; T = T3; break;
  }
  int k0 = blockIdx.x * 64, n0 = blockIdx.y * 64;
  int r = threadIdx.x >> 6, c = threadIdx.x & 63;
#pragma unroll
  for (int i = 0; i < 16; ++i)
    t[r + i * 4][c] = W[(size_t)(k0 + r + i * 4) * E_ + n0 + c];
  __syncthreads();
#pragma unroll
  for (int i = 0; i < 16; ++i)
    T[(size_t)(n0 + r + i * 4) * E_ + k0 + c] = f2bf(t[c][r + i * 4]);
}

// ---------------- bf16 GEMM: C[M,N] = A[M,K] * Bt[N,K]^T (m97-style) ----------------
// MODE 0: C f32 row-major. MODE 1: C bf16 row-major. MODE 3: C bf16 * 0.125*log2e.
// MODE 2: A=WvT[e][m], Bt=mb[n][m]; C[e][n] -> vt[((n>>11)*16+(e>>6))*64+(e&63)][n&2047]
template <int MODE>
__global__ __launch_bounds__(256) void gemm_bt(const u16* __restrict__ A,
                                               const u16* __restrict__ Bt,
                                               void* __restrict__ C,
                                               int M, int N, int Kc) {
  __shared__ u16 As[128 * 32];
  __shared__ u16 Bs[128 * 32];
  const int tid = threadIdx.x;
  const int w = tid >> 6, l = tid & 63;
  const int wr = w >> 1, wc = w & 1;
  const int lr = l & 15, lg = l >> 4;
  const int m0 = blockIdx.x * 128, n0 = blockIdx.y * 128;
  const int e = w * 1024 + l * 8;
  const int row0 = e >> 5, col0 = e & 31;

  f32x4 acc[4][4];
#pragma unroll
  for (int mt = 0; mt < 4; ++mt)
#pragma unroll
    for (int nt = 0; nt < 4; ++nt)
      acc[mt][nt] = (f32x4){0.f, 0.f, 0.f, 0.f};

  for (int k0 = 0; k0 < Kc; k0 += 32) {
    __syncthreads();
    gload16(A  + (size_t)(m0 + row0) * Kc + k0 + col0, &As[e]);
    gload16(Bt + (size_t)(n0 + row0) * Kc + k0 + col0, &Bs[e]);
    gload16(A  + (size_t)(m0 + row0 + 16) * Kc + k0 + col0, &As[e + 512]);
    gload16(Bt + (size_t)(n0 + row0 + 16) * Kc + k0 + col0, &Bs[e + 512]);
    __syncthreads();

    bf16x8 a[4], b[4];
#pragma unroll
    for (int mt = 0; mt < 4; ++mt)
      a[mt] = *reinterpret_cast<const bf16x8*>(&As[(wr * 64 + mt * 16 + lr) * 32 + lg * 8]);
#pragma unroll
    for (int nt = 0; nt < 4; ++nt)
      b[nt] = *reinterpret_cast<const bf16x8*>(&Bs[(wc * 64 + nt * 16 + lr) * 32 + lg * 8]);
#pragma unroll
    for (int mt = 0; mt < 4; ++mt)
#pragma unroll
      for (int nt = 0; nt < 4; ++nt)
        acc[mt][nt] = __builtin_amdgcn_mfma_f32_16x16x32_bf16(a[mt], b[nt], acc[mt][nt], 0, 0, 0);
  }

#pragma unroll
  for (int mt = 0; mt < 4; ++mt) {
#pragma unroll
    for (int nt = 0; nt < 4; ++nt) {
      int col = n0 + wc * 64 + nt * 16 + lr;
#pragma unroll
      for (int j = 0; j < 4; ++j) {
        int row = m0 + wr * 64 + mt * 16 + lg * 4 + j;
        float v = acc[mt][nt][j];
        if (MODE == 0) {
          ((float*)C)[(size_t)row * N + col] = v;
        } else if (MODE == 1) {
          ((u16*)C)[(size_t)row * N + col] = f2bf(v);
        } else if (MODE == 3) {
          ((u16*)C)[(size_t)row * N + col] = f2bf(v * (0.125f * LOG2E));
        } else {
          ((u16*)C)[((size_t)((col >> 11) * 16 + (row >> 6)) * 64 + (row & 63)) * 2048 + (col & 2047)] = f2bf(v);
        }
      }
    }
  }
}

// ---------------- fused biased flash attention ----------------
// QBLK=64 (4 waves x 16 q-rows), KVBLK=64, double-buffered LDS (1 barrier/iter),
// swapped QK^T, in-register P, head-pinned XCD mapping, exp2-domain softmax,
// defer-max (T13), native bf16 casts.
__global__ __launch_bounds__(256, 4) void attn_kernel(const u16* __restrict__ qp,
                                                      const u16* __restrict__ kp,
                                                      const u16* __restrict__ vT,
                                                      const float* __restrict__ bias2,
                                                      u16* __restrict__ out) {
  __shared__ u16 k_lds[2][64 * 64];
  __shared__ u16 v_lds[2][64 * 64];

  const int blk = blockIdx.x;
  const int hg = blk & 63, qt = blk >> 6;     // blk%8 == h%8 -> head pinned to XCD
  const int b = hg >> 4, h = hg & 15;
  const int tid = threadIdx.x;
  const int w = tid >> 6, l = tid & 63;
  const int lr = l & 15, lg = l >> 4;

  // Q fragments straight from global: lane holds Q[q=qt*64+w*16+lr][hd=ks*32+lg*8+..]
  bf16x8 qfrag[2];
#pragma unroll
  for (int ks = 0; ks < 2; ++ks)
    qfrag[ks] = *reinterpret_cast<const bf16x8*>(
        qp + (size_t)(b * Q_ + qt * 64 + w * 16 + lr) * E_ + h * 64 + ks * 32 + lg * 8);

  f32x4 O[4];
#pragma unroll
  for (int ht = 0; ht < 4; ++ht) O[ht] = (f32x4){0.f, 0.f, 0.f, 0.f};
  float m_run = -1e30f, l_run = 0.f;
  const float* bias_b = bias2 + (size_t)b * K_;
  const u16* kbase = kp + (size_t)b * K_ * E_ + h * 64;
  const u16* vbase = vT + (size_t)(b * H_ + h) * HD_ * K_;

  const int e0 = tid * 8, e1 = tid * 8 + 2048;
  const int r0 = e0 >> 6, c0 = e0 & 63;
  const int r1 = e1 >> 6, c1 = e1 & 63;
  const int s0 = r0 * 64 + (c0 ^ ((r0 & 7) << 3));
  const int s1 = r1 * 64 + (c1 ^ ((r1 & 7) << 3));

  // prologue: stage tile 0 -> buf0
  {
    uint4 k0v = *reinterpret_cast<const uint4*>(kbase + (size_t)r0 * E_ + c0);
    uint4 k1v = *reinterpret_cast<const uint4*>(kbase + (size_t)r1 * E_ + c1);
    uint4 v0v = *reinterpret_cast<const uint4*>(vbase + (size_t)r0 * K_ + c0);
    uint4 v1v = *reinterpret_cast<const uint4*>(vbase + (size_t)r1 * K_ + c1);
    *reinterpret_cast<uint4*>(&k_lds[0][s0]) = k0v;
    *reinterpret_cast<uint4*>(&k_lds[0][s1]) = k1v;
    *reinterpret_cast<uint4*>(&v_lds[0][s0]) = v0v;
    *reinterpret_cast<uint4*>(&v_lds[0][s1]) = v1v;
  }
  __syncthreads();

  const int NT = K_ / 64;
  for (int t = 0; t < NT; ++t) {
    const int cur = t & 1;
    // issue next tile's global loads early (latency hides under compute)
    uint4 kv0, kv1, vv0, vv1;
    if (t + 1 < NT) {
      int kk0 = (t + 1) * 64;
      kv0 = *reinterpret_cast<const uint4*>(kbase + (size_t)(kk0 + r0) * E_ + c0);
      kv1 = *reinterpret_cast<const uint4*>(kbase + (size_t)(kk0 + r1) * E_ + c1);
      vv0 = *reinterpret_cast<const uint4*>(vbase + (size_t)r0 * K_ + kk0 + c0);
      vv1 = *reinterpret_cast<const uint4*>(vbase + (size_t)r1 * K_ + kk0 + c1);
    }

    // swapped QK^T: lane holds S^T[k=ct*16+lg*4+j][q=w*16+lr] (log2 domain)
    f32x4 S[4];
    __builtin_amdgcn_s_setprio(1);
#pragma unroll
    for (int ct = 0; ct < 4; ++ct) {
      int row = ct * 16 + lr;
      bf16x8 kb0 = *reinterpret_cast<const bf16x8*>(&k_lds[cur][row * 64 + ((lg * 8) ^ ((row & 7) << 3))]);
      bf16x8 kb1 = *reinterpret_cast<const bf16x8*>(&k_lds[cur][row * 64 + ((32 + lg * 8) ^ ((row & 7) << 3))]);
      f32x4 s = (f32x4){0.f, 0.f, 0.f, 0.f};
      s = __builtin_amdgcn_mfma_f32_16x16x32_bf16(kb0, qfrag[0], s, 0, 0, 0);
      s = __builtin_amdgcn_mfma_f32_16x16x32_bf16(kb1, qfrag[1], s, 0, 0, 0);
      S[ct] = s;
    }
    __builtin_amdgcn_s_setprio(0);
    const float* bt = bias_b + t * 64;
#pragma unroll
    for (int ct = 0; ct < 4; ++ct) {
      float4 bv = *reinterpret_cast<const float4*>(&bt[ct * 16 + lg * 4]);
      S[ct][0] += bv.x; S[ct][1] += bv.y; S[ct][2] += bv.z; S[ct][3] += bv.w;
    }

    // tile max (tree, max3-friendly)
    float tm0 = fmaxf(fmaxf(S[0][0], S[0][1]), fmaxf(S[0][2], S[0][3]));
    float tm1 = fmaxf(fmaxf(S[1][0], S[1][1]), fmaxf(S[1][2], S[1][3]));
    float tm2 = fmaxf(fmaxf(S[2][0], S[2][1]), fmaxf(S[2][2], S[2][3]));
    float tm3 = fmaxf(fmaxf(S[3][0], S[3][1]), fmaxf(S[3][2], S[3][3]));
    float tmax = fmaxf(fmaxf(tm0, tm1), fmaxf(tm2, tm3));
    tmax = fmaxf(tmax, __shfl_xor(tmax, 16, 64));
    tmax = fmaxf(tmax, __shfl_xor(tmax, 32, 64));

    // defer-max: only rescale when some row's max grew past THR (wave-uniform branch)
    if (!__all(tmax <= m_run + DEFER_THR)) {
      float m_new = fmaxf(m_run, tmax);
      float mf = exp2f(m_run - m_new);
      m_run = m_new;
      l_run *= mf;
      float mfj[4];
#pragma unroll
      for (int j = 0; j < 4; ++j) mfj[j] = __shfl(mf, (l & 48) | (lg * 4 + j), 64);
#pragma unroll
      for (int ht = 0; ht < 4; ++ht)
#pragma unroll
        for (int j = 0; j < 4; ++j) O[ht][j] *= mfj[j];
    }

    // P = 2^(S - m_run), bf16 pack (native casts), tree psum
    float ps01 = 0.f, ps23 = 0.f;
    bf16x4 pf[4];
#pragma unroll
    for (int ct = 0; ct < 4; ++ct) {
      float p0 = exp2f(S[ct][0] - m_run);
      float p1 = exp2f(S[ct][1] - m_run);
      float p2 = exp2f(S[ct][2] - m_run);
      float p3 = exp2f(S[ct][3] - m_run);
      pf[ct][0] = bfc(p0); pf[ct][1] = bfc(p1);
      pf[ct][2] = bfc(p2); pf[ct][3] = bfc(p3);
      ps01 += (p0 + p1); ps23 += (p2 + p3);
    }
    float psum = ps01 + ps23;
    psum += __shfl_xor(psum, 16, 64);
    psum += __shfl_xor(psum, 32, 64);
    l_run += psum;

    // PV: P already in 16x16x16 A-fragment layout
    __builtin_amdgcn_s_setprio(1);
#pragma unroll
    for (int ct = 0; ct < 4; ++ct)
#pragma unroll
      for (int ht = 0; ht < 4; ++ht) {
        int row = ht * 16 + lr;
        bf16x4 vb = *reinterpret_cast<const bf16x4*>(
            &v_lds[cur][row * 64 + ((ct * 16 + lg * 4) ^ ((row & 7) << 3))]);
        O[ht] = __builtin_amdgcn_mfma_f32_16x16x16bf16_1k(pf[ct], vb, O[ht], 0, 0, 0);
      }
    __builtin_amdgcn_s_setprio(0);

    // write next tile into the other buffer
    if (t + 1 < NT) {
      *reinterpret_cast<uint4*>(&k_lds[cur ^ 1][s0]) = kv0;
      *reinterpret_cast<uint4*>(&k_lds[cur ^ 1][s1]) = kv1;
      *reinterpret_cast<uint4*>(&v_lds[cur ^ 1][s0]) = vv0;
      *reinterpret_cast<uint4*>(&v_lds[cur ^ 1][s1]) = vv1;
    }
    __syncthreads();
  }

  // epilogue: O[q=lg*4+j][hd=ht*16+lr] /= l(q)
  float inv = 1.f / l_run;
  float invj[4];
#pragma unroll
  for (int j = 0; j < 4; ++j) invj[j] = __shfl(inv, (l & 48) | (lg * 4 + j), 64);
#pragma unroll
  for (int j = 0; j < 4; ++j) {
    int row = b * Q_ + qt * 64 + w * 16 + lg * 4 + j;
#pragma unroll
    for (int ht = 0; ht < 4; ++ht)
      out[(size_t)row * E_ + h * 64 + ht * 16 + lr] = (u16)bfc(O[ht][j] * invj[j]);
  }
}

// ---------------- launch ----------------
extern "C" void kernel_launch(void* const* d_in, const int* in_sizes, int n_in,
                              void* d_out, int out_size, void* d_ws, size_t ws_size,
                              hipStream_t stream) {
  const float* query  = (const float*)d_in[0];
  const float* memory = (const float*)d_in[1];
  const float* bias   = (const float*)d_in[2];
  const float* Wq     = (const float*)d_in[3];
  const float* Wk     = (const float*)d_in[4];
  const float* Wv     = (const float*)d_in[5];
  const float* Wo     = (const float*)d_in[6];
  float* out = (float*)d_out;

  char* p = (char*)d_ws;
  u16* qb    = (u16*)p; p += (size_t)B_ * Q_ * E_ * 2;   // 8 MiB
  u16* mb    = (u16*)p; p += (size_t)B_ * K_ * E_ * 2;   // 16 MiB
  u16* wqt   = (u16*)p; p += (size_t)E_ * E_ * 2;        // 2 MiB
  u16* wkt   = (u16*)p; p += (size_t)E_ * E_ * 2;
  u16* wvt   = (u16*)p; p += (size_t)E_ * E_ * 2;
  u16* wot   = (u16*)p; p += (size_t)E_ * E_ * 2;
  u16* qproj = (u16*)p; p += (size_t)B_ * Q_ * E_ * 2;   // 8 MiB
  u16* kproj = (u16*)p; p += (size_t)B_ * K_ * E_ * 2;   // 16 MiB
  u16* vt    = (u16*)p; p += (size_t)B_ * K_ * E_ * 2;   // 16 MiB
  u16* attn  = (u16*)p; p += (size_t)B_ * Q_ * E_ * 2;   // 8 MiB
  float* bias2 = (float*)p; p += (size_t)B_ * K_ * 4;    // 32 KiB (total ~80 MiB)

  int prep_threads = NQ8 + NM8 + NBI;
  prep_kernel<<<(prep_threads + 255) / 256, 256, 0, stream>>>(query, memory, bias, qb, mb, bias2);

  transpose_cvt4<<<dim3(16, 16, 4), 256, 0, stream>>>(Wq, Wk, Wv, Wo, wqt, wkt, wvt, wot);

  gemm_bt<3><<<dim3(32, 8), 256, 0, stream>>>(qb, wqt, qproj, B_ * Q_, E_, E_);   // q-proj * 0.125*log2e
  gemm_bt<1><<<dim3(64, 8), 256, 0, stream>>>(mb, wkt, kproj, B_ * K_, E_, E_);   // k-proj
  gemm_bt<2><<<dim3(8, 64), 256, 0, stream>>>(wvt, mb, vt, E_, B_ * K_, E_);      // v-proj -> vT

  attn_kernel<<<B_ * H_ * (Q_ / 64), 256, 0, stream>>>(qproj, kproj, vt, bias2, attn);

  gemm_bt<0><<<dim3(32, 8), 256, 0, stream>>>(attn, wot, out, B_ * Q_, E_, E_);
}